// Round 11
// baseline (1531.187 us; speedup 1.0000x reference)
//
#include <hip/hip_runtime.h>
#include <math.h>
#include <stddef.h>

#define NLAYER 24
#define NEMBD  1024
#define NFFN   4096
#define NB     256
#define NT     256           // wave 0 = act-stager/poller; waves 1-3 = compute
#define LN_EPS 1e-5f

#define OUT_SA (NEMBD)
#define OUT_SB (NEMBD + NLAYER*NEMBD)
#define OUT_SC (NEMBD + 2*NLAYER*NEMBD)
#define OUT_SD (NEMBD + 3*NLAYER*NEMBD)

typedef unsigned long long u64;
typedef unsigned u32;

// tagged-word queues in workspace (u64: tag<<32 | float bits)
#define QX_OFF    0        // 1024
#define QKVR_OFF  1024     // 3072
#define QSXX_OFF  4096     // 1024
#define QKFB_OFF  5120     // 4096
#define QTOTAL    9216

// LDS float offsets
#define LACT 0             // 4096: staged acts (x / kvr / sxx / kf)
#define LMSK 4096          // 3072: masked vectors
#define LLN  7168          // 8:  LN partials
#define LXL  7176          // 4:  x[b*4+r] local       (s1 -> s2)
#define LSXL 7180          // 4:  sxx[b*4+r] local     (s2 -> s4)
#define LRFL 7184          // 4:  rf[b*4+r] local      (s3 -> s4)
#define LPT  7188          // 12: s4 K-split partials
#define SMTOT 7200

struct Params {
  const float *x, *state, *ln1w, *ln1b, *ln2w, *ln2b, *td, *tf, *kktk, *vvtv, *rrtr;
  const float *key, *outputv, *tmk, *tmr, *kffn, *rffn, *vffn;
  float *out;
  u64 *q;
};

__device__ __forceinline__ float wred(float v) {
#pragma unroll
  for (int o = 32; o > 0; o >>= 1) v += __shfl_xor(v, o, 64);
  return v;
}
__device__ __forceinline__ float dot4(float4 a, float4 b) {
  return a.x*b.x + a.y*b.y + a.z*b.z + a.w*b.w;
}
__device__ __forceinline__ float fcomp(float4 v, int j) {   // literal j only
  return j == 0 ? v.x : (j == 1 ? v.y : (j == 2 ? v.z : v.w));
}
__device__ __forceinline__ u64 qload(const u64* a) {
  return __hip_atomic_load(a, __ATOMIC_RELAXED, __HIP_MEMORY_SCOPE_AGENT);
}
__device__ __forceinline__ void qput(u64* a, float v, u32 tag) {
  u64 w = ((u64)tag << 32) | (u64)__float_as_uint(v);
  __hip_atomic_store(a, w, __ATOMIC_RELAXED, __HIP_MEMORY_SCOPE_AGENT);
}
__device__ __forceinline__ u32   qtag(u64 w) { return (u32)(w >> 32); }
__device__ __forceinline__ float qval(u64 w) { return __uint_as_float((u32)w); }

// intra-block barrier: LDS ordering only; compute waves' weight stream
// (vmcnt) is untouched and keeps flowing while they wait here.
__device__ __forceinline__ void lbar() {
  asm volatile("s_waitcnt lgkmcnt(0)" ::: "memory");
  __builtin_amdgcn_s_barrier();
  asm volatile("" ::: "memory");
}

// wave-0 poll: N words/lane (word idx = c*64+lane), wait tag >= TG, stage to LDS
#define POLLN(N, QBASE, TG, LOFF)                                              \
  do {                                                                         \
    u64 pw_[N]; long cc_ = 0;                                                  \
    for (;;) {                                                                 \
      bool ok_ = true;                                                         \
      _Pragma("unroll")                                                        \
      for (int c_ = 0; c_ < N; ++c_) pw_[c_] = qload((QBASE) + c_*64 + lane);  \
      _Pragma("unroll")                                                        \
      for (int c_ = 0; c_ < N; ++c_) ok_ &= (qtag(pw_[c_]) >= (TG));           \
      if (__all(ok_)) break;                                                   \
      __builtin_amdgcn_s_sleep(1);                                             \
      if (++cc_ > (1L << 20)) break;  /* safety: wrong beats hang */           \
    }                                                                          \
    _Pragma("unroll")                                                          \
    for (int c_ = 0; c_ < N; ++c_) sm[(LOFF) + c_*64 + lane] = qval(pw_[c_]);  \
  } while (0)

__global__ void __launch_bounds__(NT, 1)
rwkv_persistent(Params p) {
  const int b    = blockIdx.x;
  const int t    = threadIdx.x;
  const int wid  = t >> 6;
  const int lane = t & 63;
  const int i0   = t * 4;
  const bool w0  = (wid == 0);
  const int cw   = wid - 1;          // 0..2 for compute waves

  __shared__ float sm[SMTOT];

  u64* QX   = p.q + QX_OFF;
  u64* QKVR = p.q + QKVR_OFF;
  u64* QSXX = p.q + QSXX_OFF;
  u64* QKFB = p.q + QKFB_OFF;

  // double-buffered weight regs: A = stages 1,3; B = stages 2,4
  float4 wA[28], wB[24];
  float4 prA[6], prB[4];

  auto params1 = [&](int L) {
    const int o = L * NEMBD + i0;
    prA[0] = *(const float4*)&p.ln1w[o];
    prA[1] = *(const float4*)&p.ln1b[o];
    prA[2] = *(const float4*)&p.state[0 * NLAYER * NEMBD + o];
    prA[3] = *(const float4*)&p.kktk[o];
    prA[4] = *(const float4*)&p.vvtv[o];
    prA[5] = *(const float4*)&p.rrtr[o];
  };
  auto params2 = [&](int L) {
    const int o = L * NEMBD + i0;
    prB[0] = *(const float4*)&p.tf[o];
    prB[1] = *(const float4*)&p.state[1 * NLAYER * NEMBD + o];
    prB[2] = *(const float4*)&p.state[2 * NLAYER * NEMBD + o];
    prB[3] = *(const float4*)&p.td[o];
  };
  auto params3 = [&](int L) {
    const int o = L * NEMBD + i0;
    prA[0] = *(const float4*)&p.ln2w[o];
    prA[1] = *(const float4*)&p.ln2b[o];
    prA[2] = *(const float4*)&p.state[3 * NLAYER * NEMBD + o];
    prA[3] = *(const float4*)&p.tmk[o];
    prA[4] = *(const float4*)&p.tmr[o];
  };
  auto weights1 = [&](int L) {       // key: 4 rows x 4 -> wA[0..15]
    const float* W = p.key + (size_t)L * 3 * NEMBD * NEMBD
                   + (size_t)(b * 12 + cw * 4) * NEMBD + lane * 4;
#pragma unroll
    for (int q = 0; q < 4; ++q)
#pragma unroll
      for (int jj = 0; jj < 4; ++jj)
        wA[q * 4 + jj] = *(const float4*)&W[(size_t)q * NEMBD + jj * 256];
  };
  auto weights2 = [&](int L) {       // outputv: 2/1/1 rows -> wB[0..7]
#pragma unroll
    for (int rr = 0; rr < 2; ++rr) {
      if (cw == 0 || rr == 0) {
        const int r = (cw == 0) ? rr : (cw + 1);
        const float* W = p.outputv + ((size_t)L * NEMBD + b * 4 + r) * NEMBD + lane * 4;
#pragma unroll
        for (int jj = 0; jj < 4; ++jj)
          wB[rr * 4 + jj] = *(const float4*)&W[jj * 256];
      }
    }
  };
  auto weights3 = [&](int L) {       // kffn/rffn: 7/7/6 rows -> wA[0..27]
#pragma unroll
    for (int e = 0; e < 7; ++e) {
      const int sidx = cw * 7 + e;
      if (sidx < 20) {
        const float* W = (sidx < 16)
          ? p.kffn + ((size_t)L * NFFN  + b * 16 + sidx) * NEMBD
          : p.rffn + ((size_t)L * NEMBD + b * 4 + (sidx - 16)) * NEMBD;
        W += lane * 4;
#pragma unroll
        for (int jj = 0; jj < 4; ++jj)
          wA[e * 4 + jj] = *(const float4*)&W[jj * 256];
      }
    }
  };
  auto weights4 = [&](int L) {       // vffn: 4 rows x 6/5/5 K-chunks -> wB[0..23]
    const int jb = (cw == 0) ? 0 : ((cw == 1) ? 6 : 11);
    const int jn = (cw == 0) ? 6 : 5;
#pragma unroll
    for (int r = 0; r < 4; ++r) {
      const float* W = p.vffn + ((size_t)L * NEMBD + b * 4 + r) * NFFN + lane * 4;
#pragma unroll
      for (int c = 0; c < 6; ++c) if (c < jn)
        wB[r * 6 + c] = *(const float4*)&W[(jb + c) * 256];
    }
  };

  // prologue: 2-deep — stage-1 and stage-2 bundles in flight before loop
  params1(0); params2(0);
  if (!w0) { weights1(0); weights2(0); }

  for (int l = 0; l < NLAYER; ++l) {
    const u32 t1 = (u32)(4 * l + 1), t2 = t1 + 1, t3 = t1 + 2, t4 = t1 + 3;
    const bool w1 = (b == (l * 4 + 0) % NB);
    const bool w2 = (b == (l * 4 + 1) % NB);
    const bool w3 = (b == (l * 4 + 2) % NB);

    // ================= STAGE 1: x -> ln1 -> masks -> kvr GEMV =============
    {
      if (w0) {
        if (l == 0) {
#pragma unroll
          for (int c = 0; c < 16; ++c)
            sm[LACT + c * 64 + lane] = p.x[c * 64 + lane];
        } else {
          POLLN(16, QX, (u32)(4 * l), LACT);
        }
      }
      lbar();                                    // acts ready
      float xa[4];
#pragma unroll
      for (int j = 0; j < 4; ++j) xa[j] = sm[LACT + i0 + j];
      float s = xa[0] + xa[1] + xa[2] + xa[3];
      float q = xa[0]*xa[0] + xa[1]*xa[1] + xa[2]*xa[2] + xa[3]*xa[3];
      s = wred(s); q = wred(q);
      if (lane == 0) { sm[LLN + wid] = s; sm[LLN + 4 + wid] = q; }
      lbar();                                    // LN partials
      float m  = (sm[LLN+0] + sm[LLN+1] + sm[LLN+2] + sm[LLN+3]) * (1.f / NEMBD);
      float tq = (sm[LLN+4] + sm[LLN+5] + sm[LLN+6] + sm[LLN+7]) * (1.f / NEMBD);
      float rs = rsqrtf(tq - m * m + LN_EPS);
#pragma unroll
      for (int j = 0; j < 4; ++j) {
        int i = i0 + j;
        float xy  = (xa[j] - m) * rs * fcomp(prA[0], j) + fcomp(prA[1], j);
        float sav = fcomp(prA[2], j);
        sm[LMSK + i]        = xy + fcomp(prA[3], j) * sav;
        sm[LMSK + 1024 + i] = xy + fcomp(prA[4], j) * sav;
        sm[LMSK + 2048 + i] = xy + fcomp(prA[5], j) * sav;
        if (w1) p.out[OUT_SA + l * NEMBD + i] = xy;   // statea_new
      }
      if (t < 4) sm[LXL + t] = sm[LACT + b * 4 + t];  // x local for stage 2
      lbar();                                    // masks ready
      if (!w0) {
        const int r0 = b * 12 + cw * 4;
#pragma unroll
        for (int qq = 0; qq < 4; ++qq) {
          const float* mv = &sm[LMSK + ((r0 + qq) >> 10) * 1024];
          float a = 0.f;
#pragma unroll
          for (int jj = 0; jj < 4; ++jj)
            a += dot4(wA[qq * 4 + jj], *(const float4*)&mv[lane * 4 + jj * 256]);
          a = wred(a);
          if (lane == 0) qput(&QKVR[r0 + qq], a, t1);
        }
        params3(l); weights3(l);                 // bundle(s3) -> A
      } else {
        params3(l);
      }
    }

    // ================= STAGE 2: kvr -> wkv -> outputv GEMV ================
    {
      if (w0) POLLN(48, QKVR, t1, LACT);
      lbar();                                    // acts ready
      float kk[4], vv[4], rv[4];
#pragma unroll
      for (int j = 0; j < 4; ++j) {
        kk[j] = sm[LACT + i0 + j];
        vv[j] = sm[LACT + 1024 + i0 + j];
        rv[j] = sm[LACT + 2048 + i0 + j];
      }
#pragma unroll
      for (int j = 0; j < 4; ++j) {
        float sb = fcomp(prB[1], j), sc = fcomp(prB[2], j);
        float etfk = expf(fcomp(prB[0], j) + kk[j]);
        float er   = expf(rv[j]);
        // sc*er + exp(tf+k+r) + sc + etfk == (sc+etfk)*(1+er)
        sm[LMSK + i0 + j] = (sb + etfk * vv[j]) / ((sc + etfk) * (1.f + er));
        if (w2) {
          float ek = expf(kk[j]), ed = expf(fcomp(prB[3], j));
          p.out[OUT_SB + l * NEMBD + i0 + j] = sb * ed + ek * vv[j];
          p.out[OUT_SC + l * NEMBD + i0 + j] = sc * ed + ek;
        }
      }
      lbar();                                    // w vector ready
      if (!w0) {
#pragma unroll
        for (int rr = 0; rr < 2; ++rr) {
          if (cw == 0 || rr == 0) {
            const int r = (cw == 0) ? rr : (cw + 1);
            float a = 0.f;
#pragma unroll
            for (int jj = 0; jj < 4; ++jj)
              a += dot4(wB[rr * 4 + jj], *(const float4*)&sm[LMSK + lane * 4 + jj * 256]);
            a = wred(a);
            if (lane == 0) {
              float sxx = sm[LXL + r] + a;
              qput(&QSXX[b * 4 + r], sxx, t2);
              sm[LSXL + r] = sxx;                // local for stage 4
            }
          }
        }
        weights4(l);                             // bundle(s4) -> B
      }
    }

    // ================= STAGE 3: sxx -> ln2 -> masks -> ffn GEMV ===========
    {
      if (w0) POLLN(16, QSXX, t2, LACT);
      lbar();                                    // acts ready
      float xa[4];
#pragma unroll
      for (int j = 0; j < 4; ++j) xa[j] = sm[LACT + i0 + j];
      float s = xa[0] + xa[1] + xa[2] + xa[3];
      float q = xa[0]*xa[0] + xa[1]*xa[1] + xa[2]*xa[2] + xa[3]*xa[3];
      s = wred(s); q = wred(q);
      if (lane == 0) { sm[LLN + wid] = s; sm[LLN + 4 + wid] = q; }
      lbar();                                    // LN partials
      float m  = (sm[LLN+0] + sm[LLN+1] + sm[LLN+2] + sm[LLN+3]) * (1.f / NEMBD);
      float tq = (sm[LLN+4] + sm[LLN+5] + sm[LLN+6] + sm[LLN+7]) * (1.f / NEMBD);
      float rs = rsqrtf(tq - m * m + LN_EPS);
#pragma unroll
      for (int j = 0; j < 4; ++j) {
        int i = i0 + j;
        float xx  = (xa[j] - m) * rs * fcomp(prA[0], j) + fcomp(prA[1], j);
        float sdv = fcomp(prA[2], j);
        sm[LMSK + i]        = xx + fcomp(prA[3], j) * sdv;
        sm[LMSK + 1024 + i] = xx + fcomp(prA[4], j) * sdv;
        if (w3) p.out[OUT_SD + l * NEMBD + i] = xx;   // stated_new
      }
      lbar();                                    // masks ready
      if (!w0) {
#pragma unroll
        for (int e = 0; e < 7; ++e) {
          const int sidx = cw * 7 + e;
          if (sidx < 20) {
            const float* mv = &sm[LMSK + ((sidx < 16) ? 0 : 1024)];
            float a = 0.f;
#pragma unroll
            for (int jj = 0; jj < 4; ++jj)
              a += dot4(wA[e * 4 + jj], *(const float4*)&mv[lane * 4 + jj * 256]);
            a = wred(a);
            if (lane == 0) {
              if (sidx < 16) { float kv = fmaxf(a, 0.f); qput(&QKFB[b * 16 + sidx], kv * kv, t3); }
              else           { sm[LRFL + (sidx - 16)] = expf(a); }   // block-local
            }
          }
        }
        if (l + 1 < NLAYER) { params1(l + 1); weights1(l + 1); }   // bundle(s1')
      } else {
        if (l + 1 < NLAYER) params1(l + 1);
      }
    }

    // ================= STAGE 4: kf -> vffn GEMV (K-split) -> x' ===========
    {
      if (w0) POLLN(64, QKFB, t3, LACT);
      lbar();                                    // acts ready
      if (!w0) {
        const int jb = (cw == 0) ? 0 : ((cw == 1) ? 6 : 11);
        const int jn = (cw == 0) ? 6 : 5;
#pragma unroll
        for (int r = 0; r < 4; ++r) {
          float a = 0.f;
#pragma unroll
          for (int c = 0; c < 6; ++c) if (c < jn)
            a += dot4(wB[r * 6 + c], *(const float4*)&sm[LACT + lane * 4 + (jb + c) * 256]);
          a = wred(a);
          if (lane == 0) sm[LPT + r * 3 + cw] = a;
        }
        if (l + 1 < NLAYER) { params2(l + 1); weights2(l + 1); }   // bundle(s2')
      } else {
        if (l + 1 < NLAYER) params2(l + 1);
      }
      lbar();                                    // partials ready
      if (w0 && lane < 4) {
        float tot = sm[LPT + lane * 3] + sm[LPT + lane * 3 + 1] + sm[LPT + lane * 3 + 2];
        float xn  = sm[LSXL + lane] + tot / (sm[LRFL + lane] + 1.f);
        if (l == NLAYER - 1) p.out[b * 4 + lane] = xn;   // final x_out
        else                 qput(&QX[b * 4 + lane], xn, t4);
      }
    }
  }
}

__global__ void rwkv_init(u64* q) {
  for (int i = 0; i < 36; ++i)
    q[threadIdx.x * 36 + i] = 0ull;
}

extern "C" void kernel_launch(void* const* d_in, const int* in_sizes, int n_in,
                              void* d_out, int out_size, void* d_ws, size_t ws_size,
                              hipStream_t stream) {
  Params p;
  p.x       = (const float*)d_in[0];
  p.state   = (const float*)d_in[1];
  p.ln1w    = (const float*)d_in[2];
  p.ln1b    = (const float*)d_in[3];
  p.ln2w    = (const float*)d_in[4];
  p.ln2b    = (const float*)d_in[5];
  p.td      = (const float*)d_in[6];
  p.tf      = (const float*)d_in[7];
  p.kktk    = (const float*)d_in[8];
  p.vvtv    = (const float*)d_in[9];
  p.rrtr    = (const float*)d_in[10];
  p.key     = (const float*)d_in[11];
  p.outputv = (const float*)d_in[12];
  p.tmk     = (const float*)d_in[13];
  p.tmr     = (const float*)d_in[14];
  p.kffn    = (const float*)d_in[15];
  p.rffn    = (const float*)d_in[16];
  p.vffn    = (const float*)d_in[17];
  p.out     = (float*)d_out;
  p.q       = (u64*)d_ws;            // 9216 u64 = 73728 B

  rwkv_init<<<1, NB, 0, stream>>>(p.q);
  rwkv_persistent<<<NB, NT, 0, stream>>>(p);
}

// Round 12
// 929.419 us; speedup vs baseline: 1.6475x; 1.6475x over previous
//
#include <hip/hip_runtime.h>
#include <math.h>
#include <stddef.h>

#define NLAYER 24
#define NEMBD  1024
#define NFFN   4096
#define NB     256
#define NT     256           // wave 0 = poller/param-stager; waves 1-3 = compute
#define LN_EPS 1e-5f

#define OUT_SA (NEMBD)
#define OUT_SB (NEMBD + NLAYER*NEMBD)
#define OUT_SC (NEMBD + 2*NLAYER*NEMBD)
#define OUT_SD (NEMBD + 3*NLAYER*NEMBD)

typedef unsigned long long u64;
typedef unsigned u32;

// tagged-word queues in workspace (u64: tag<<32 | float bits)
#define QX_OFF    0        // 1024
#define QKVR_OFF  1024     // 3072
#define QSXX_OFF  4096     // 1024
#define QKFB_OFF  5120     // 4096

// LDS float offsets
#define LACT 0             // 4096: staged acts (x / kvr / sxx / kf)
#define LMSK 4096          // 3072: masked vectors / w vector
#define LPRM 7168          // 6144: staged params (up to 6 vectors)
#define LLN  13312         // 8:  LN partials
#define LXL  13320         // 4:  x[b*4+r] local    (s1 -> s2)
#define LSXL 13324         // 4:  sxx[b*4+r] local  (s2 -> s4)
#define LRFL 13328         // 4:  rf[b*4+r] local   (s3 -> s4)
#define LPT  13332         // 12: s4 K-split partials
#define LW3  13344         // 3 x 7168: stage-3 weight slabs (28KB/wave)
#define SMTOT (13344 + 3*7168)   // 34848 floats = 139392 B

struct Params {
  const float *x, *state, *ln1w, *ln1b, *ln2w, *ln2b, *td, *tf, *kktk, *vvtv, *rrtr;
  const float *key, *outputv, *tmk, *tmr, *kffn, *rffn, *vffn;
  float *out;
  u64 *q;
};

__device__ __forceinline__ float wred(float v) {
#pragma unroll
  for (int o = 32; o > 0; o >>= 1) v += __shfl_xor(v, o, 64);
  return v;
}
__device__ __forceinline__ float dot4(float4 a, float4 b) {
  return a.x*b.x + a.y*b.y + a.z*b.z + a.w*b.w;
}
__device__ __forceinline__ u64 qload(const u64* a) {
  return __hip_atomic_load(a, __ATOMIC_RELAXED, __HIP_MEMORY_SCOPE_AGENT);
}
__device__ __forceinline__ void qput(u64* a, float v, u32 tag) {
  u64 w = ((u64)tag << 32) | (u64)__float_as_uint(v);
  __hip_atomic_store(a, w, __ATOMIC_RELAXED, __HIP_MEMORY_SCOPE_AGENT);
}
__device__ __forceinline__ u32   qtag(u64 w) { return (u32)(w >> 32); }
__device__ __forceinline__ float qval(u64 w) { return __uint_as_float((u32)w); }

// async global->LDS, 16B/lane: LDS dest = wave-uniform base + lane*16
__device__ __forceinline__ void stage16(const float* g, float* l) {
  __builtin_amdgcn_global_load_lds(
      (const __attribute__((address_space(1))) unsigned int*)g,
      (__attribute__((address_space(3))) unsigned int*)l, 16, 0, 0);
}

// intra-block barrier: LDS ordering only; weight vmem stays in flight
__device__ __forceinline__ void lbar() {
  asm volatile("s_waitcnt lgkmcnt(0)" ::: "memory");
  __builtin_amdgcn_s_barrier();
  asm volatile("" ::: "memory");
}

// wave-0 chunked poll: 16 words/lane -> 1024 words; stage values into LDS
#define POLL16(QBASE, TG, LOFF)                                               \
  do {                                                                        \
    u64 pw_[16]; long cc_ = 0;                                                \
    for (;;) {                                                                \
      bool ok_ = true;                                                        \
      _Pragma("unroll")                                                       \
      for (int c_ = 0; c_ < 16; ++c_) pw_[c_] = qload((QBASE) + c_*64 + lane);\
      _Pragma("unroll")                                                       \
      for (int c_ = 0; c_ < 16; ++c_) ok_ &= (qtag(pw_[c_]) >= (TG));         \
      if (__all(ok_)) break;                                                  \
      __builtin_amdgcn_s_sleep(1);                                            \
      if (++cc_ > (1L << 20)) break;  /* safety: wrong beats hang */          \
    }                                                                         \
    _Pragma("unroll")                                                         \
    for (int c_ = 0; c_ < 16; ++c_) sm[(LOFF) + c_*64 + lane] = qval(pw_[c_]);\
  } while (0)

__global__ void __launch_bounds__(NT, 1)
rwkv_persistent(Params p) {
  const int b    = blockIdx.x;
  const int t    = threadIdx.x;
  const int wid  = t >> 6;
  const int lane = t & 63;
  const int i0   = t * 4;
  const bool w0  = (wid == 0);
  const int cw   = wid - 1;          // 0..2 for compute waves

  __shared__ float sm[SMTOT];

  u64* QX   = p.q + QX_OFF;
  u64* QKVR = p.q + QKVR_OFF;
  u64* QSXX = p.q + QSXX_OFF;
  u64* QKFB = p.q + QKFB_OFF;

  float4 wA[16];    // s1 key (4 rows x 4)
  float4 wB[24];    // s2 outputv (2/1/1 rows -> [0..7]) and s4 vffn (4 rows x 6/5/5)

  auto loadW1 = [&](int L) {
    const float* W = p.key + (size_t)L * 3 * NEMBD * NEMBD
                   + (size_t)(b * 12 + cw * 4) * NEMBD + lane * 4;
#pragma unroll
    for (int q = 0; q < 4; ++q)
#pragma unroll
      for (int jj = 0; jj < 4; ++jj)
        wA[q * 4 + jj] = *(const float4*)&W[(size_t)q * NEMBD + jj * 256];
  };
  auto loadW2 = [&](int L) {
#pragma unroll
    for (int rr = 0; rr < 2; ++rr) {
      if (cw == 0 || rr == 0) {
        const int r = (cw == 0) ? rr : (cw + 1);
        const float* W = p.outputv + ((size_t)L * NEMBD + b * 4 + r) * NEMBD + lane * 4;
#pragma unroll
        for (int jj = 0; jj < 4; ++jj)
          wB[rr * 4 + jj] = *(const float4*)&W[jj * 256];
      }
    }
  };
  auto stageW3 = [&](int L) {        // 7/7/6 rows -> own LDS slab, async
    float* slab = &sm[LW3 + cw * 7168];
#pragma unroll
    for (int e = 0; e < 7; ++e) {
      const int sidx = cw * 7 + e;
      if (sidx < 20) {
        const float* W = (sidx < 16)
          ? p.kffn + ((size_t)L * NFFN  + b * 16 + sidx) * NEMBD
          : p.rffn + ((size_t)L * NEMBD + b * 4 + (sidx - 16)) * NEMBD;
#pragma unroll
        for (int c = 0; c < 4; ++c)
          stage16(W + c * 256 + lane * 4, slab + (e * 4 + c) * 256);
      }
    }
  };
  auto loadW4 = [&](int L) {         // vffn 4 rows x 6/5/5 K-chunks
    const int jb = (cw == 0) ? 0 : ((cw == 1) ? 6 : 11);
    const int jn = (cw == 0) ? 6 : 5;
#pragma unroll
    for (int r = 0; r < 4; ++r) {
      const float* W = p.vffn + ((size_t)L * NEMBD + b * 4 + r) * NFFN + lane * 4;
#pragma unroll
      for (int c = 0; c < 6; ++c) if (c < jn)
        wB[r * 6 + c] = *(const float4*)&W[(jb + c) * 256];
    }
  };
  // wave-0 param staging: copy vector src+L*NEMBD into LPRM slot v
  auto stagePrm = [&](const float* src, int L, int v) {
#pragma unroll
    for (int c = 0; c < 4; ++c) {
      float4 tmp = *(const float4*)&src[L * NEMBD + c * 256 + lane * 4];
      *(float4*)&sm[LPRM + v * 1024 + c * 256 + lane * 4] = tmp;
    }
  };

  // prologue: 2-deep start — s1 and s2 bundles in flight
  if (!w0) { loadW1(0); loadW2(0); }

  for (int l = 0; l < NLAYER; ++l) {
    const u32 t1 = (u32)(4 * l + 1), t2 = t1 + 1, t3 = t1 + 2, t4 = t1 + 3;
    const bool w1 = (b == (l * 4 + 0) % NB);
    const bool w2 = (b == (l * 4 + 1) % NB);
    const bool w3 = (b == (l * 4 + 2) % NB);

    // ========== STAGE 1: x -> ln1 -> masks -> key GEMV ==========
    {
      if (w0) {
        stagePrm(p.ln1w, l, 0); stagePrm(p.ln1b, l, 1);
        stagePrm(p.state + 0 * NLAYER * NEMBD, l, 2);
        stagePrm(p.kktk, l, 3); stagePrm(p.vvtv, l, 4); stagePrm(p.rrtr, l, 5);
        if (l == 0) {
#pragma unroll
          for (int c = 0; c < 16; ++c)
            sm[LACT + c * 64 + lane] = p.x[c * 64 + lane];
        } else {
          POLL16(QX, (u32)(4 * l), LACT);
        }
      }
      lbar();                                  // acts + params ready
      float xa[4];
#pragma unroll
      for (int j = 0; j < 4; ++j) xa[j] = sm[LACT + i0 + j];
      float s = xa[0] + xa[1] + xa[2] + xa[3];
      float q = xa[0]*xa[0] + xa[1]*xa[1] + xa[2]*xa[2] + xa[3]*xa[3];
      s = wred(s); q = wred(q);
      if (lane == 0) { sm[LLN + wid] = s; sm[LLN + 4 + wid] = q; }
      lbar();                                  // LN partials
      float m  = (sm[LLN+0] + sm[LLN+1] + sm[LLN+2] + sm[LLN+3]) * (1.f / NEMBD);
      float tq = (sm[LLN+4] + sm[LLN+5] + sm[LLN+6] + sm[LLN+7]) * (1.f / NEMBD);
      float rs = rsqrtf(tq - m * m + LN_EPS);
#pragma unroll
      for (int j = 0; j < 4; ++j) {
        int i = i0 + j;
        float xy  = (xa[j] - m) * rs * sm[LPRM + i] + sm[LPRM + 1024 + i];
        float sav = sm[LPRM + 2048 + i];
        sm[LMSK + i]        = xy + sm[LPRM + 3072 + i] * sav;
        sm[LMSK + 1024 + i] = xy + sm[LPRM + 4096 + i] * sav;
        sm[LMSK + 2048 + i] = xy + sm[LPRM + 5120 + i] * sav;
        if (w1) p.out[OUT_SA + l * NEMBD + i] = xy;   // statea_new
      }
      if (t < 4) sm[LXL + t] = sm[LACT + b * 4 + t];  // x local for s2
      lbar();                                  // masks ready
      if (!w0) {
        const int r0 = b * 12 + cw * 4;
#pragma unroll
        for (int qq = 0; qq < 4; ++qq) {
          const float* mv = &sm[LMSK + ((r0 + qq) >> 10) * 1024];
          float a = 0.f;
#pragma unroll
          for (int jj = 0; jj < 4; ++jj)
            a += dot4(wA[qq * 4 + jj], *(const float4*)&mv[lane * 4 + jj * 256]);
          a = wred(a);
          if (lane == 0) qput(&QKVR[r0 + qq], a, t1);
        }
        stageW3(l);                            // async -> LDS, 2-stage depth
      }
    }

    // ========== STAGE 2: kvr -> wkv -> outputv GEMV ==========
    {
      if (w0) {
        stagePrm(p.tf, l, 0);
        stagePrm(p.state + 1 * NLAYER * NEMBD, l, 1);
        stagePrm(p.state + 2 * NLAYER * NEMBD, l, 2);
        stagePrm(p.td, l, 3);
        POLL16(QKVR, t1, LACT);
        POLL16(QKVR + 1024, t1, LACT + 1024);
        POLL16(QKVR + 2048, t1, LACT + 2048);
      }
      lbar();                                  // acts + params ready
#pragma unroll
      for (int j = 0; j < 4; ++j) {
        int i = i0 + j;
        float kk = sm[LACT + i];
        float vv = sm[LACT + 1024 + i];
        float rv = sm[LACT + 2048 + i];
        float sb = sm[LPRM + 1024 + i], sc = sm[LPRM + 2048 + i];
        float etfk = expf(sm[LPRM + i] + kk);
        float er   = expf(rv);
        // sc*er + exp(tf+k+r) + sc + etfk == (sc+etfk)*(1+er)
        sm[LMSK + i] = (sb + etfk * vv) / ((sc + etfk) * (1.f + er));
        if (w2) {
          float ek = expf(kk), ed = expf(sm[LPRM + 3072 + i]);
          p.out[OUT_SB + l * NEMBD + i] = sb * ed + ek * vv;
          p.out[OUT_SC + l * NEMBD + i] = sc * ed + ek;
        }
      }
      lbar();                                  // w vector ready
      if (!w0) {
#pragma unroll
        for (int rr = 0; rr < 2; ++rr) {
          if (cw == 0 || rr == 0) {
            const int r = (cw == 0) ? rr : (cw + 1);
            float a = 0.f;
#pragma unroll
            for (int jj = 0; jj < 4; ++jj)
              a += dot4(wB[rr * 4 + jj], *(const float4*)&sm[LMSK + lane * 4 + jj * 256]);
            a = wred(a);
            if (lane == 0) {
              float sxx = sm[LXL + r] + a;
              qput(&QSXX[b * 4 + r], sxx, t2);
              sm[LSXL + r] = sxx;
            }
          }
        }
        loadW4(l);                             // regs, 2-stage depth
      }
    }

    // ========== STAGE 3: sxx -> ln2 -> masks -> ffn GEMV (LDS weights) ====
    {
      if (w0) {
        stagePrm(p.ln2w, l, 0); stagePrm(p.ln2b, l, 1);
        stagePrm(p.state + 3 * NLAYER * NEMBD, l, 2);
        stagePrm(p.tmk, l, 3); stagePrm(p.tmr, l, 4);
        POLL16(QSXX, t2, LACT);
      }
      lbar();                                  // acts + params ready
      float xa[4];
#pragma unroll
      for (int j = 0; j < 4; ++j) xa[j] = sm[LACT + i0 + j];
      float s = xa[0] + xa[1] + xa[2] + xa[3];
      float q = xa[0]*xa[0] + xa[1]*xa[1] + xa[2]*xa[2] + xa[3]*xa[3];
      s = wred(s); q = wred(q);
      if (lane == 0) { sm[LLN + wid] = s; sm[LLN + 4 + wid] = q; }
      lbar();                                  // LN partials
      float m  = (sm[LLN+0] + sm[LLN+1] + sm[LLN+2] + sm[LLN+3]) * (1.f / NEMBD);
      float tq = (sm[LLN+4] + sm[LLN+5] + sm[LLN+6] + sm[LLN+7]) * (1.f / NEMBD);
      float rs = rsqrtf(tq - m * m + LN_EPS);
#pragma unroll
      for (int j = 0; j < 4; ++j) {
        int i = i0 + j;
        float xx  = (xa[j] - m) * rs * sm[LPRM + i] + sm[LPRM + 1024 + i];
        float sdv = sm[LPRM + 2048 + i];
        sm[LMSK + i]        = xx + sm[LPRM + 3072 + i] * sdv;
        sm[LMSK + 1024 + i] = xx + sm[LPRM + 4096 + i] * sdv;
        if (w3) p.out[OUT_SD + l * NEMBD + i] = xx;   // stated_new
      }
      lbar();                                  // masks ready
      if (!w0) {
        // W3 (gl2lds) retired once <=20 outstanding: the youngest >=20 ops
        // are W4 reg loads (24/20/20) issued after W3 -> safe bound.
        asm volatile("s_waitcnt vmcnt(20)" ::: "memory");
        __builtin_amdgcn_sched_barrier(0);
        const int slab = LW3 + cw * 7168;
#pragma unroll
        for (int e = 0; e < 7; ++e) {
          const int sidx = cw * 7 + e;
          if (sidx < 20) {
            const float* mv = &sm[LMSK + ((sidx < 16) ? 0 : 1024)];
            float a = 0.f;
#pragma unroll
            for (int jj = 0; jj < 4; ++jj)
              a += dot4(*(const float4*)&sm[slab + (e * 4 + jj) * 256 + lane * 4],
                        *(const float4*)&mv[lane * 4 + jj * 256]);
            a = wred(a);
            if (lane == 0) {
              if (sidx < 16) { float kv = fmaxf(a, 0.f); qput(&QKFB[b * 16 + sidx], kv * kv, t3); }
              else           { sm[LRFL + (sidx - 16)] = expf(a); }
            }
          }
        }
        if (l + 1 < NLAYER) loadW1(l + 1);     // wA refill, 2-stage depth
      }
    }

    // ========== STAGE 4: kf -> vffn GEMV (K-split) -> x' ==========
    {
      if (w0) {
        POLL16(QKFB, t3, LACT);
        POLL16(QKFB + 1024, t3, LACT + 1024);
        POLL16(QKFB + 2048, t3, LACT + 2048);
        POLL16(QKFB + 3072, t3, LACT + 3072);
      }
      lbar();                                  // acts ready
      if (!w0) {
        const int jb = (cw == 0) ? 0 : ((cw == 1) ? 6 : 11);
        const int jn = (cw == 0) ? 6 : 5;
#pragma unroll
        for (int r = 0; r < 4; ++r) {
          float a = 0.f;
#pragma unroll
          for (int c = 0; c < 6; ++c) if (c < jn)
            a += dot4(wB[r * 6 + c], *(const float4*)&sm[LACT + lane * 4 + (jb + c) * 256]);
          a = wred(a);
          if (lane == 0) sm[LPT + r * 3 + cw] = a;
        }
        if (l + 1 < NLAYER) loadW2(l + 1);     // wB refill for s2'
      }
      lbar();                                  // partials ready
      if (w0 && lane < 4) {
        float tot = sm[LPT + lane * 3] + sm[LPT + lane * 3 + 1] + sm[LPT + lane * 3 + 2];
        float xn  = sm[LSXL + lane] + tot / (sm[LRFL + lane] + 1.f);
        if (l == NLAYER - 1) p.out[b * 4 + lane] = xn;   // final x_out
        else                 qput(&QX[b * 4 + lane], xn, t4);
      }
    }
  }
}

__global__ void rwkv_init(u64* q) {
  for (int i = 0; i < 36; ++i)
    q[threadIdx.x * 36 + i] = 0ull;
}

extern "C" void kernel_launch(void* const* d_in, const int* in_sizes, int n_in,
                              void* d_out, int out_size, void* d_ws, size_t ws_size,
                              hipStream_t stream) {
  Params p;
  p.x       = (const float*)d_in[0];
  p.state   = (const float*)d_in[1];
  p.ln1w    = (const float*)d_in[2];
  p.ln1b    = (const float*)d_in[3];
  p.ln2w    = (const float*)d_in[4];
  p.ln2b    = (const float*)d_in[5];
  p.td      = (const float*)d_in[6];
  p.tf      = (const float*)d_in[7];
  p.kktk    = (const float*)d_in[8];
  p.vvtv    = (const float*)d_in[9];
  p.rrtr    = (const float*)d_in[10];
  p.key     = (const float*)d_in[11];
  p.outputv = (const float*)d_in[12];
  p.tmk     = (const float*)d_in[13];
  p.tmr     = (const float*)d_in[14];
  p.kffn    = (const float*)d_in[15];
  p.rffn    = (const float*)d_in[16];
  p.vffn    = (const float*)d_in[17];
  p.out     = (float*)d_out;
  p.q       = (u64*)d_ws;            // 9216 u64 = 73728 B

  rwkv_init<<<1, NB, 0, stream>>>(p.q);
  rwkv_persistent<<<NB, NT, 0, stream>>>(p);
}

// Round 13
// 450.473 us; speedup vs baseline: 3.3991x; 2.0632x over previous
//
#include <hip/hip_runtime.h>
#include <math.h>
#include <stddef.h>

#define NLAYER 24
#define NEMBD  1024
#define NFFN   4096
#define NB     256
#define NT     256
#define LN_EPS 1e-5f

#define OUT_SA (NEMBD)
#define OUT_SB (NEMBD + NLAYER*NEMBD)
#define OUT_SC (NEMBD + 2*NLAYER*NEMBD)
#define OUT_SD (NEMBD + 3*NLAYER*NEMBD)

typedef unsigned long long u64;
typedef unsigned u32;

// tagged-word queues (u64: tag<<32 | float bits), data IS the sync signal
#define QX_OFF    0        // 1024: x' per layer
#define QW_OFF    1024     // 1024: w vector (producer-side wkv!)
#define QSXX_OFF  2048     // 1024: sxx
#define QKFB_OFF  3072     // 4096: kf
#define QTOTAL    7168

// LDS float offsets
#define LMSK  0            // 3072: ln masks / staged w vector
#define LACT  3072         // 4096: staged kf
#define LFF   7168         // 4 x 5120: per-wave FFN weight slabs (80 KB)
#define LLN   27648        // 8: LN partials
#define LXL   27656        // 4: x[b*4+r]   (s1 -> s2)
#define LSXL  27660        // 4: sxx[b*4+r] (s2 -> s4)
#define LRFL  27664        // 4: rf[b*4+r]  (s3 -> s4)
#define LPT   27668        // 16: s4 K-split partials [r*4+wave]
#define SMTOT 27684        // 110736 B

struct Params {
  const float *x, *state, *ln1w, *ln1b, *ln2w, *ln2b, *td, *tf, *kktk, *vvtv, *rrtr;
  const float *key, *outputv, *tmk, *tmr, *kffn, *rffn, *vffn;
  float *out;
  u64 *q;
};

__device__ __forceinline__ float wred(float v) {
#pragma unroll
  for (int o = 32; o > 0; o >>= 1) v += __shfl_xor(v, o, 64);
  return v;
}
__device__ __forceinline__ float dot4(float4 a, float4 b) {
  return a.x*b.x + a.y*b.y + a.z*b.z + a.w*b.w;
}
__device__ __forceinline__ float fcomp(float4 v, int j) {   // literal j only
  return j == 0 ? v.x : (j == 1 ? v.y : (j == 2 ? v.z : v.w));
}
__device__ __forceinline__ u64 qload(const u64* a) {
  return __hip_atomic_load(a, __ATOMIC_RELAXED, __HIP_MEMORY_SCOPE_AGENT);
}
__device__ __forceinline__ void qput(u64* a, float v, u32 tag) {
  u64 w = ((u64)tag << 32) | (u64)__float_as_uint(v);
  __hip_atomic_store(a, w, __ATOMIC_RELAXED, __HIP_MEMORY_SCOPE_AGENT);
}
__device__ __forceinline__ u32   qtag(u64 w) { return (u32)(w >> 32); }
__device__ __forceinline__ float qval(u64 w) { return __uint_as_float((u32)w); }

// async global->LDS, 16B/lane: dest = wave-uniform base + lane*16
__device__ __forceinline__ void stage16(const float* g, float* l) {
  __builtin_amdgcn_global_load_lds(
      (const __attribute__((address_space(1))) unsigned int*)g,
      (__attribute__((address_space(3))) unsigned int*)l, 16, 0, 0);
}

// intra-block barrier: LDS ordering only; weight vmem stays in flight
__device__ __forceinline__ void lbar() {
  asm volatile("s_waitcnt lgkmcnt(0)" ::: "memory");
  __builtin_amdgcn_s_barrier();
  asm volatile("" ::: "memory");
}

// per-thread poll of its own 4 consecutive words
#define POLL4(QB, IDX, TG, OUTA)                                              \
  do {                                                                        \
    u64 a0_, a1_, a2_, a3_; long cc_ = 0;                                     \
    for (;;) {                                                                \
      a0_ = qload((QB) + (IDX) + 0); a1_ = qload((QB) + (IDX) + 1);           \
      a2_ = qload((QB) + (IDX) + 2); a3_ = qload((QB) + (IDX) + 3);           \
      if (qtag(a0_) >= (TG) && qtag(a1_) >= (TG) &&                           \
          qtag(a2_) >= (TG) && qtag(a3_) >= (TG)) break;                      \
      __builtin_amdgcn_s_sleep(1);                                            \
      if (++cc_ > (1L << 20)) break;  /* safety: wrong beats hang */          \
    }                                                                         \
    OUTA[0] = qval(a0_); OUTA[1] = qval(a1_);                                 \
    OUTA[2] = qval(a2_); OUTA[3] = qval(a3_);                                 \
  } while (0)

__global__ void __launch_bounds__(NT, 1)
rwkv_persistent(Params p) {
  const int b    = blockIdx.x;
  const int t    = threadIdx.x;
  const int wid  = t >> 6;
  const int lane = t & 63;
  const int i0   = t * 4;
  const int myi  = b * 4 + wid;     // this wave's owned vector index

  __shared__ float sm[SMTOT];

  u64* QX   = p.q + QX_OFF;
  u64* QW   = p.q + QW_OFF;
  u64* QSXX = p.q + QSXX_OFF;
  u64* QKFB = p.q + QKFB_OFF;

  float4 wKEY[12];   // s1: k,v,r rows for index myi (3 rows x 4 chunks)
  float4 wOV[4];     // s2: outputv row myi
  float4 wVF[16];    // s4: vffn 4 rows x this wave's 4 K-chunks
  float4 pA[6];      // s1 params
  float4 pC[5];      // s3 params
  float s_tf, s_sb, s_sc, s_td;   // lane0 wkv scalars for index myi

  auto loadKEY = [&](int L) {
#pragma unroll
    for (int mth = 0; mth < 3; ++mth) {
      const float* W = p.key + ((size_t)L * 3 + mth) * NEMBD * NEMBD
                     + (size_t)myi * NEMBD + lane * 4;
#pragma unroll
      for (int c = 0; c < 4; ++c)
        wKEY[mth * 4 + c] = *(const float4*)&W[c * 256];
    }
  };
  auto loadOV = [&](int L) {
    const float* W = p.outputv + ((size_t)L * NEMBD + myi) * NEMBD + lane * 4;
#pragma unroll
    for (int c = 0; c < 4; ++c)
      wOV[c] = *(const float4*)&W[c * 256];
  };
  auto loadVF = [&](int L) {
#pragma unroll
    for (int r = 0; r < 4; ++r) {
      const float* W = p.vffn + ((size_t)L * NEMBD + b * 4 + r) * NFFN + lane * 4;
#pragma unroll
      for (int c = 0; c < 4; ++c)
        wVF[r * 4 + c] = *(const float4*)&W[(wid * 4 + c) * 256];
    }
  };
  auto stageFF = [&](int L) {       // 4 kffn rows + 1 rffn row -> own LDS slab
    float* slab = &sm[LFF + wid * 5120];
#pragma unroll
    for (int q = 0; q < 4; ++q) {
      const float* W = p.kffn + ((size_t)L * NFFN + b * 16 + wid * 4 + q) * NEMBD;
#pragma unroll
      for (int c = 0; c < 4; ++c)
        stage16(W + c * 256 + lane * 4, slab + q * 1024 + c * 256);
    }
    const float* Wr = p.rffn + ((size_t)L * NEMBD + myi) * NEMBD;
#pragma unroll
    for (int c = 0; c < 4; ++c)
      stage16(Wr + c * 256 + lane * 4, slab + 4096 + c * 256);
  };
  auto loadPA = [&](int L) {
    const int o = L * NEMBD + i0;
    pA[0] = *(const float4*)&p.ln1w[o];
    pA[1] = *(const float4*)&p.ln1b[o];
    pA[2] = *(const float4*)&p.state[0 * NLAYER * NEMBD + o];
    pA[3] = *(const float4*)&p.kktk[o];
    pA[4] = *(const float4*)&p.vvtv[o];
    pA[5] = *(const float4*)&p.rrtr[o];
    if (lane == 0) {
      const int ix = L * NEMBD + myi;
      s_tf = p.tf[ix];
      s_sb = p.state[1 * NLAYER * NEMBD + ix];
      s_sc = p.state[2 * NLAYER * NEMBD + ix];
      s_td = p.td[ix];
    }
  };
  auto loadPC = [&](int L) {
    const int o = L * NEMBD + i0;
    pC[0] = *(const float4*)&p.ln2w[o];
    pC[1] = *(const float4*)&p.ln2b[o];
    pC[2] = *(const float4*)&p.state[3 * NLAYER * NEMBD + o];
    pC[3] = *(const float4*)&p.tmk[o];
    pC[4] = *(const float4*)&p.tmr[o];
  };

  // prologue: layer-0 s1/s2 bundles + params in flight
  loadPA(0); loadKEY(0); loadOV(0);

  for (int l = 0; l < NLAYER; ++l) {
    const u32 t1 = (u32)(4 * l + 1), t2 = t1 + 1, t3 = t1 + 2, t4 = t1 + 3;

    // ===== STAGE 1: x -> ln1 -> masks -> k/v/r dots -> wkv (producer) =====
    {
      float xa[4];
      if (l == 0) {
        float4 x4 = *(const float4*)&p.x[i0];
        xa[0] = x4.x; xa[1] = x4.y; xa[2] = x4.z; xa[3] = x4.w;
      } else {
        POLL4(QX, i0, (u32)(4 * l), xa);
      }
      if (t == b) {                       // own x slice local for stage 2
#pragma unroll
        for (int j = 0; j < 4; ++j) sm[LXL + j] = xa[j];
      }
      float s = xa[0] + xa[1] + xa[2] + xa[3];
      float q = xa[0]*xa[0] + xa[1]*xa[1] + xa[2]*xa[2] + xa[3]*xa[3];
      s = wred(s); q = wred(q);
      if (lane == 0) { sm[LLN + wid] = s; sm[LLN + 4 + wid] = q; }
      lbar();
      float m  = (sm[LLN+0] + sm[LLN+1] + sm[LLN+2] + sm[LLN+3]) * (1.f / NEMBD);
      float tq = (sm[LLN+4] + sm[LLN+5] + sm[LLN+6] + sm[LLN+7]) * (1.f / NEMBD);
      float rs = rsqrtf(tq - m * m + LN_EPS);
#pragma unroll
      for (int j = 0; j < 4; ++j) {
        int i = i0 + j;
        float xy  = (xa[j] - m) * rs * fcomp(pA[0], j) + fcomp(pA[1], j);
        float sav = fcomp(pA[2], j);
        sm[LMSK + i]        = xy + fcomp(pA[3], j) * sav;
        sm[LMSK + 1024 + i] = xy + fcomp(pA[4], j) * sav;
        sm[LMSK + 2048 + i] = xy + fcomp(pA[5], j) * sav;
        if (t == b) p.out[OUT_SA + l * NEMBD + i] = xy;   // statea: own slice
      }
      lbar();                                             // masks ready
      float a0 = 0.f, a1 = 0.f, a2 = 0.f;
#pragma unroll
      for (int c = 0; c < 4; ++c) {
        int col = lane * 4 + c * 256;
        a0 += dot4(wKEY[c],     *(const float4*)&sm[LMSK + col]);
        a1 += dot4(wKEY[4 + c], *(const float4*)&sm[LMSK + 1024 + col]);
        a2 += dot4(wKEY[8 + c], *(const float4*)&sm[LMSK + 2048 + col]);
      }
      a0 = wred(a0); a1 = wred(a1); a2 = wred(a2);
      if (lane == 0) {                    // producer-side wkv combine
        float etfk = expf(s_tf + a0);
        float er   = expf(a2);
        // sc*er + exp(tf+k+r) + sc + etfk == (sc+etfk)*(1+er)
        float wv = (s_sb + etfk * a1) / ((s_sc + etfk) * (1.f + er));
        qput(&QW[myi], wv, t1);
        float ek = expf(a0), ed = expf(s_td);
        p.out[OUT_SB + l * NEMBD + myi] = s_sb * ed + ek * a1;   // distributed
        p.out[OUT_SC + l * NEMBD + myi] = s_sc * ed + ek;
      }
      stageFF(l); loadPC(l);              // next bundles, in flight
      lbar();                             // stage end (LMSK reuse barrier)
    }

    // ===== STAGE 2: w -> outputv dot -> sxx =====
    {
      float wv[4];
      POLL4(QW, i0, t1, wv);
#pragma unroll
      for (int j = 0; j < 4; ++j) sm[LMSK + i0 + j] = wv[j];
      lbar();                             // w vector staged
      float acc = 0.f;
#pragma unroll
      for (int c = 0; c < 4; ++c)
        acc += dot4(wOV[c], *(const float4*)&sm[LMSK + lane * 4 + c * 256]);
      acc = wred(acc);
      if (lane == 0) {
        float sxx = sm[LXL + wid] + acc;
        qput(&QSXX[myi], sxx, t2);
        sm[LSXL + wid] = sxx;             // local for stage 4
      }
      loadVF(l);                          // s4 bundle, in flight
      lbar();                             // stage end
    }

    // ===== STAGE 3: sxx -> ln2 -> masks -> ffn dots (LDS weights) =====
    {
      float xa[4];
      POLL4(QSXX, i0, t2, xa);
      float s = xa[0] + xa[1] + xa[2] + xa[3];
      float q = xa[0]*xa[0] + xa[1]*xa[1] + xa[2]*xa[2] + xa[3]*xa[3];
      s = wred(s); q = wred(q);
      if (lane == 0) { sm[LLN + wid] = s; sm[LLN + 4 + wid] = q; }
      lbar();
      float m  = (sm[LLN+0] + sm[LLN+1] + sm[LLN+2] + sm[LLN+3]) * (1.f / NEMBD);
      float tq = (sm[LLN+4] + sm[LLN+5] + sm[LLN+6] + sm[LLN+7]) * (1.f / NEMBD);
      float rs = rsqrtf(tq - m * m + LN_EPS);
#pragma unroll
      for (int j = 0; j < 4; ++j) {
        int i = i0 + j;
        float xx  = (xa[j] - m) * rs * fcomp(pC[0], j) + fcomp(pC[1], j);
        float sdv = fcomp(pC[2], j);
        sm[LMSK + i]        = xx + fcomp(pC[3], j) * sdv;
        sm[LMSK + 1024 + i] = xx + fcomp(pC[4], j) * sdv;
        if (t == b) p.out[OUT_SD + l * NEMBD + i] = xx;   // stated: own slice
      }
      lbar();                             // masks ready (FF slab landed: the
                                          // poll-value use above drained all
                                          // older vmem incl. stageFF)
      const float* slab = &sm[LFF + wid * 5120];
#pragma unroll
      for (int q2 = 0; q2 < 4; ++q2) {
        float a = 0.f;
#pragma unroll
        for (int c = 0; c < 4; ++c) {
          int col = lane * 4 + c * 256;
          a += dot4(*(const float4*)&slab[q2 * 1024 + col],
                    *(const float4*)&sm[LMSK + col]);
        }
        a = wred(a);
        if (lane == 0) {
          float kv = fmaxf(a, 0.f);
          qput(&QKFB[b * 16 + wid * 4 + q2], kv * kv, t3);
        }
      }
      {
        float a = 0.f;
#pragma unroll
        for (int c = 0; c < 4; ++c) {
          int col = lane * 4 + c * 256;
          a += dot4(*(const float4*)&slab[4096 + col],
                    *(const float4*)&sm[LMSK + 1024 + col]);
        }
        a = wred(a);
        if (lane == 0) sm[LRFL + wid] = expf(a);   // block-local only
      }
      if (l + 1 < NLAYER) { loadKEY(l + 1); loadPA(l + 1); }
      lbar();                             // stage end
    }

    // ===== STAGE 4: kf -> vffn dot (K-split) -> x' =====
    {
#pragma unroll
      for (int c = 0; c < 4; ++c) {
        float ka[4];
        POLL4(QKFB, c * 1024 + i0, t3, ka);
#pragma unroll
        for (int j = 0; j < 4; ++j) sm[LACT + c * 1024 + i0 + j] = ka[j];
      }
      lbar();                             // kf staged
#pragma unroll
      for (int r = 0; r < 4; ++r) {
        float a = 0.f;
#pragma unroll
        for (int c = 0; c < 4; ++c)
          a += dot4(wVF[r * 4 + c],
                    *(const float4*)&sm[LACT + lane * 4 + (wid * 4 + c) * 256]);
        a = wred(a);
        if (lane == 0) sm[LPT + r * 4 + wid] = a;
      }
      if (l + 1 < NLAYER) loadOV(l + 1);
      lbar();                             // partials ready
      if (t < 4) {
        float tot = sm[LPT + t * 4 + 0] + sm[LPT + t * 4 + 1]
                  + sm[LPT + t * 4 + 2] + sm[LPT + t * 4 + 3];
        float xn = sm[LSXL + t] + tot / (sm[LRFL + t] + 1.f);
        if (l == NLAYER - 1) p.out[b * 4 + t] = xn;   // final x_out
        else                 qput(&QX[b * 4 + t], xn, t4);
      }
    }
  }
}

__global__ void rwkv_init(u64* q) {
  for (int i = 0; i < 28; ++i)
    q[threadIdx.x * 28 + i] = 0ull;
}

extern "C" void kernel_launch(void* const* d_in, const int* in_sizes, int n_in,
                              void* d_out, int out_size, void* d_ws, size_t ws_size,
                              hipStream_t stream) {
  Params p;
  p.x       = (const float*)d_in[0];
  p.state   = (const float*)d_in[1];
  p.ln1w    = (const float*)d_in[2];
  p.ln1b    = (const float*)d_in[3];
  p.ln2w    = (const float*)d_in[4];
  p.ln2b    = (const float*)d_in[5];
  p.td      = (const float*)d_in[6];
  p.tf      = (const float*)d_in[7];
  p.kktk    = (const float*)d_in[8];
  p.vvtv    = (const float*)d_in[9];
  p.rrtr    = (const float*)d_in[10];
  p.key     = (const float*)d_in[11];
  p.outputv = (const float*)d_in[12];
  p.tmk     = (const float*)d_in[13];
  p.tmr     = (const float*)d_in[14];
  p.kffn    = (const float*)d_in[15];
  p.rffn    = (const float*)d_in[16];
  p.vffn    = (const float*)d_in[17];
  p.out     = (float*)d_out;
  p.q       = (u64*)d_ws;            // 7168 u64 = 57344 B

  rwkv_init<<<1, NB, 0, stream>>>(p.q);
  rwkv_persistent<<<NB, NT, 0, stream>>>(p);
}